// Round 8
// baseline (184.168 us; speedup 1.0000x reference)
//
#include <hip/hip_runtime.h>
#include <math.h>

// Problem constants (B=8, T=4096, D=1024, G=2, N=320, Cd=512)
#define M_ROWS 32768   // B*T
#define KDIM   1024    // D
#define GN     640     // G*N
#define NGRP   2
#define NCODES 320
#define CD     512

#define BM 64            // rows per block
#define BK 32            // k-tile
#define NT (KDIM / BK)   // 32
#define THREADS 256      // 4 waves: 2 (M) x 2 (N)
#define SLAB 20480       // bytes per (tile, group) B slab

typedef __attribute__((ext_vector_type(8))) short bf16x8;   // 8 bf16 = 4 VGPR
typedef __attribute__((ext_vector_type(4))) float f32x4;

__device__ __forceinline__ unsigned short f2bf(float f) {
    unsigned u = __builtin_bit_cast(unsigned, f);
    return (unsigned short)((u + 0x7FFFu + ((u >> 16) & 1u)) >> 16);  // RNE
}
__device__ __forceinline__ unsigned pk2(float lo, float hi) {
    return (unsigned)f2bf(lo) | ((unsigned)f2bf(hi) << 16);
}
// async global->LDS, 16B/lane; LDS dest = wave-uniform base + lane*16
__device__ __forceinline__ void gll16(const void* g, void* l) {
    __builtin_amdgcn_global_load_lds(
        (const __attribute__((address_space(1))) unsigned int*)g,
        (__attribute__((address_space(3))) unsigned int*)l, 16, 0, 0);
}

// ---- prepass: W[k][GN] fp32 -> Wt4 bf16, laid out so a wave's B-frag ds_read is
// LINEAR 1KB: slab(t,g) = [c16(20)][chunk(64)][8 bf16], chunk = ks*16 + colmod16,
// k = t*32 + ks*8 + j, col-in-group = c16*16 + colmod16. Zeroes counts too.
__global__ __launch_bounds__(256) void prep_kernel(const float* __restrict__ W,
                                                   unsigned short* __restrict__ Wt4,
                                                   int* __restrict__ counts) {
    const int k = blockIdx.x;                    // 0..1023
    const int t = k >> 5, ks = (k >> 3) & 3, j = k & 7;
    for (int c = threadIdx.x; c < GN; c += 256) {
        int g   = c / NCODES;
        int cl  = c % NCODES;
        int c16 = cl >> 4, cm = cl & 15;
        size_t idx = (size_t)(t * 2 + g) * 10240 + c16 * 512 + (ks * 16 + cm) * 8 + j;
        Wt4[idx] = f2bf(W[(size_t)k * GN + c]);
    }
    if (blockIdx.x == 0)
        for (int i = threadIdx.x; i < GN; i += 256) counts[i] = 0;
}

// ---- fused half-width MFMA GEMM + argmax + counts + gather.
// Counted-vmcnt pipeline: 1 raw s_barrier per tile, vmcnt never drained to 0
// in the main loop (tile t+2's 9 VMEM ops stay in flight across the barrier).
__global__ __launch_bounds__(THREADS) void gemm_fused(
    const float* __restrict__ x,              // [M, K] fp32
    const float* __restrict__ gumbel,         // [M, GN] fp32
    const float* __restrict__ codebook,       // [G, N, CD] fp32
    const unsigned short* __restrict__ Wt4,   // retiled bf16 (prep_kernel)
    const float* __restrict__ bias,           // [GN]
    float* __restrict__ out,                  // [M, G*CD] fp32 (+ loss slot)
    int* __restrict__ counts)                 // [GN]
{
    __shared__ __align__(16) char Bs[3 * SLAB];   // 60 KB: triple-buffered B tile
    __shared__ float pv[2][BM];
    __shared__ int   pi[2][BM];
    __shared__ int   idx_s[BM];

    const int tid  = threadIdx.x;
    const int wid  = tid >> 6;       // 0..3
    const int lane = tid & 63;
    const int l15  = lane & 15;
    const int l4   = lane >> 4;      // k-slot
    const int wn   = wid & 1;        // col half: 160 cols
    const int wm   = wid >> 1;       // row half: 32 rows

    // block decode: bid = xcd + 8*(g + 2*rt_local); the two groups of a row
    // tile are consecutive on the same XCD (x rows L2-shared).
    const int b    = blockIdx.x;
    const int xcd  = b & 7;
    const int q    = b >> 3;
    const int g    = q & 1;
    const int rt   = xcd * 64 + (q >> 1);     // row tile 0..511
    const int row0 = rt * BM;

    f32x4 acc[2][10];
#pragma unroll
    for (int mf = 0; mf < 2; ++mf)
#pragma unroll
        for (int nf = 0; nf < 10; ++nf) acc[mf][nf] = (f32x4){0.f, 0.f, 0.f, 0.f};

    // A: per-lane register loads; lane serves rows (wm*32+l15) and (+16), k-slice l4*8
    const float* ap0 = x + (size_t)(row0 + wm * 32 + l15) * KDIM + l4 * 8;
    const float* ap1 = ap0 + 16 * KDIM;
    // B: per-lane global src; wave wid stages bytes wid*5120..+5119 of each slab
    const char* bsrc0 = (const char*)Wt4 + (size_t)g * SLAB + wid * 5120 + (size_t)lane * 16;

    // B then A, 9 VMEM ops per tile, always this order (vmcnt counting).
#define STAGE_B(T, BUF) do {                                            \
        const char* s_ = bsrc0 + (size_t)(T) * (2 * SLAB);              \
        char* d_ = Bs + (BUF) * SLAB + wid * 5120;                      \
        gll16(s_,        d_);                                           \
        gll16(s_ + 1024, d_ + 1024);                                    \
        gll16(s_ + 2048, d_ + 2048);                                    \
        gll16(s_ + 3072, d_ + 3072);                                    \
        gll16(s_ + 4096, d_ + 4096);                                    \
    } while (0)

#define LOAD_A(T, dst) do {                                             \
        const float* p0_ = ap0 + (size_t)(T) * BK;                      \
        const float* p1_ = ap1 + (size_t)(T) * BK;                      \
        dst[0] = *reinterpret_cast<const float4*>(p0_);                 \
        dst[1] = *reinterpret_cast<const float4*>(p0_ + 4);             \
        dst[2] = *reinterpret_cast<const float4*>(p1_);                 \
        dst[3] = *reinterpret_cast<const float4*>(p1_ + 4);             \
    } while (0)

#define CONV_A(src) do {                                                \
        union { bf16x8 v; unsigned u[4]; } w0_, w1_;                    \
        w0_.u[0] = pk2(src[0].x, src[0].y);                             \
        w0_.u[1] = pk2(src[0].z, src[0].w);                             \
        w0_.u[2] = pk2(src[1].x, src[1].y);                             \
        w0_.u[3] = pk2(src[1].z, src[1].w);                             \
        w1_.u[0] = pk2(src[2].x, src[2].y);                             \
        w1_.u[1] = pk2(src[2].z, src[2].w);                             \
        w1_.u[2] = pk2(src[3].x, src[3].y);                             \
        w1_.u[3] = pk2(src[3].z, src[3].w);                             \
        af0 = w0_.v; af1 = w1_.v;                                       \
    } while (0)

#define COMPUTE(BUF) do {                                               \
        const char* bb_ = Bs + (BUF) * SLAB + wn * 10240;               \
        _Pragma("unroll")                                               \
        for (int nf = 0; nf < 10; ++nf) {                               \
            bf16x8 bfr = *reinterpret_cast<const bf16x8*>(              \
                bb_ + nf * 1024 + (size_t)lane * 16);                   \
            acc[0][nf] = __builtin_amdgcn_mfma_f32_16x16x32_bf16(       \
                af0, bfr, acc[0][nf], 0, 0, 0);                         \
            acc[1][nf] = __builtin_amdgcn_mfma_f32_16x16x32_bf16(       \
                af1, bfr, acc[1][nf], 0, 0, 0);                         \
        }                                                               \
    } while (0)

#define WAITB(N) do {                                                   \
        asm volatile("s_waitcnt vmcnt(" #N ")" ::: "memory");           \
        __builtin_amdgcn_s_barrier();                                   \
    } while (0)

// one pipeline stage: consume A(T) regs, stage tile T+2, compute tile T,
// then wait leaving exactly tile T+2's 9 ops in flight.
#define ITER(T, CUR_A, NXT_A, CUR_B, NXT_B) do {                        \
        CONV_A(CUR_A);                                                  \
        STAGE_B((T) + 2, NXT_B);                                        \
        LOAD_A((T) + 2, NXT_A);                                         \
        COMPUTE(CUR_B);                                                 \
        WAITB(9);                                                       \
    } while (0)

    float4 as0[4], as1[4], as2[4];
    bf16x8 af0, af1;

    // prologue: tiles 0,1 in flight; wait for tile 0 only (tile 1 stays in flight)
    STAGE_B(0, 0); LOAD_A(0, as0);
    STAGE_B(1, 1); LOAD_A(1, as1);
    WAITB(9);

    for (int t = 0; t < NT - 2; t += 3) {        // 30 iters, static slot/buf indices
        ITER(t,     as0, as2, 0, 2);
        ITER(t + 1, as1, as0, 1, 0);
        ITER(t + 2, as2, as1, 2, 1);
    }
    // peel tile 30 (buf 0, slot as0): drain the last 9 ops (tile 31) after compute
    CONV_A(as0);
    COMPUTE(0);
    WAITB(0);
    // peel tile 31 (buf 1, slot as1)
    CONV_A(as1);
    COMPUTE(1);

    // ---- epilogue: + bias + gumbel, per-row argmax over this wave's 160 cols
    // C/D layout: col = l15, row-in-frag = l4*4 + reg
#pragma unroll
    for (int mf = 0; mf < 2; ++mf) {
#pragma unroll
        for (int j = 0; j < 4; ++j) {
            const int lr = wm * 32 + mf * 16 + l4 * 4 + j;
            const size_t r = row0 + lr;
            const float* grow = gumbel + r * GN + g * NCODES;
            const float* brow = bias + g * NCODES;
            float best = -INFINITY;
            int bn = 0;
#pragma unroll
            for (int nf = 0; nf < 10; ++nf) {
                int n = wn * 160 + nf * 16 + l15;
                float v = acc[mf][nf][j] + brow[n] + grow[n];
                if (v > best) { best = v; bn = n; }   // nf ascending -> first max kept
            }
#pragma unroll
            for (int m = 1; m < 16; m <<= 1) {
                float ov = __shfl_xor(best, m, 64);
                int   on = __shfl_xor(bn, m, 64);
                if (ov > best || (ov == best && on < bn)) { best = ov; bn = on; }
            }
            if (l15 == 0) { pv[wn][lr] = best; pi[wn][lr] = bn; }
        }
    }
    __syncthreads();

    // combine halves: wn=1 cols all > wn=0 cols, strict > keeps lower index (np.argmax)
    if (tid < BM) {
        float v0 = pv[0][tid], v1 = pv[1][tid];
        int n = (v1 > v0) ? pi[1][tid] : pi[0][tid];
        idx_s[tid] = n;
        atomicAdd(&counts[g * NCODES + n], 1);
    }
    __syncthreads();

    // ---- gather: this block's half of out: 64 rows x 512 floats, coalesced
#pragma unroll
    for (int s = 0; s < 32; ++s) {
        int fi = tid + THREADS * s;   // 0..8191
        int lr = fi >> 7;             // /128 float4 per row
        int d4 = fi & 127;
        int n  = idx_s[lr];
        float4 cv = *reinterpret_cast<const float4*>(
            &codebook[((size_t)g * NCODES + n) * CD + d4 * 4]);
        *reinterpret_cast<float4*>(
            &out[(size_t)(row0 + lr) * KDIM + (size_t)g * CD + d4 * 4]) = cv;
    }
#undef STAGE_B
#undef LOAD_A
#undef CONV_A
#undef COMPUTE
#undef WAITB
#undef ITER
}

__global__ void loss_kernel(const int* __restrict__ counts, float* __restrict__ out_loss) {
    __shared__ float red[256];
    float sum = 0.0f;
    for (int i = threadIdx.x; i < GN; i += 256) {
        float avg = (float)counts[i] * (1.0f / (float)M_ROWS);
        sum += avg * logf(avg + 1e-7f);
    }
    red[threadIdx.x] = sum;
    __syncthreads();
    for (int s = 128; s > 0; s >>= 1) {
        if (threadIdx.x < s) red[threadIdx.x] += red[threadIdx.x + s];
        __syncthreads();
    }
    if (threadIdx.x == 0) out_loss[0] = -red[0] * (1.0f / (float)NGRP);
}

extern "C" void kernel_launch(void* const* d_in, const int* in_sizes, int n_in,
                              void* d_out, int out_size, void* d_ws, size_t ws_size,
                              hipStream_t stream) {
    const float* x        = (const float*)d_in[0];
    const float* gumbel   = (const float*)d_in[1];
    const float* codebook = (const float*)d_in[2];
    const float* W        = (const float*)d_in[3];
    const float* bias     = (const float*)d_in[4];
    float* out = (float*)d_out;

    unsigned short* Wt4 = (unsigned short*)d_ws;              // 1.31 MB retiled
    int* counts = (int*)((char*)d_ws + 1310720 + 256);        // 2.5 KB

    prep_kernel<<<dim3(KDIM), dim3(256), 0, stream>>>(W, Wt4, counts);
    gemm_fused<<<dim3(1024), dim3(THREADS), 0, stream>>>(
        x, gumbel, codebook, Wt4, bias, out, counts);
    loss_kernel<<<dim3(1), dim3(256), 0, stream>>>(
        counts, out + (size_t)M_ROWS * KDIM);
}

// Round 9
// 169.436 us; speedup vs baseline: 1.0870x; 1.0870x over previous
//
#include <hip/hip_runtime.h>
#include <math.h>

// Problem constants (B=8, T=4096, D=1024, G=2, N=320, Cd=512)
#define M_ROWS 32768   // B*T
#define KDIM   1024    // D
#define GN     640     // G*N
#define NGRP   2
#define NCODES 320
#define CD     512

#define BM 64            // rows per block (A kernel)
#define BK 64            // k-tile
#define NT (KDIM / BK)   // 16
#define QBN 160          // cols per block (one quarter of GN)
#define SLAB 20480       // bytes of one (tile, quarter) B slab: 10 colblk x 128 chunk x 16B

typedef __attribute__((ext_vector_type(8))) short bf16x8;
typedef __attribute__((ext_vector_type(4))) float f32x4;

__device__ __forceinline__ unsigned short f2bf(float f) {
    unsigned u = __builtin_bit_cast(unsigned, f);
    return (unsigned short)((u + 0x7FFFu + ((u >> 16) & 1u)) >> 16);  // RNE
}
__device__ __forceinline__ unsigned pk2(float lo, float hi) {
    return (unsigned)f2bf(lo) | ((unsigned)f2bf(hi) << 16);
}
__device__ __forceinline__ float bf2f(unsigned short u) {
    return __builtin_bit_cast(float, (unsigned)u << 16);
}
// async global->LDS, 16B/lane; LDS dest = wave-uniform base + lane*16
__device__ __forceinline__ void gll16(const void* g, void* l) {
    __builtin_amdgcn_global_load_lds(
        (const __attribute__((address_space(1))) unsigned int*)g,
        (__attribute__((address_space(3))) unsigned int*)l, 16, 0, 0);
}

// ---- prepass: W[k][GN] fp32 -> Wt3 bf16; slab(t,qq) [20KB] = [colblk(10)][chunk(128)][8]
// chunk = ks*16 + (col&15), ks = (k>>3)&7, colblk = (col%160)>>4, j = k&7, t = k>>6.
// A wave's B-frag read is then LINEAR: byte = nf*2048 + half*1024 + lane*16.
__global__ __launch_bounds__(256) void prep_kernel(const float* __restrict__ W,
                                                   unsigned short* __restrict__ Wt3,
                                                   int* __restrict__ counts) {
    const int k = blockIdx.x;                    // 0..1023
    const int t = k >> 6, ks = (k >> 3) & 7, j = k & 7;
    for (int c = threadIdx.x; c < GN; c += 256) {
        int qq = c / QBN, cl = c % QBN;
        int cb = cl >> 4, cm = cl & 15;
        size_t idx = (size_t)(t * 4 + qq) * 10240 + cb * 1024 + (ks * 16 + cm) * 8 + j;
        Wt3[idx] = f2bf(W[(size_t)k * GN + c]);
    }
    if (blockIdx.x == 0)
        for (int i = threadIdx.x; i < GN; i += 256) counts[i] = 0;
}

// ---- pass A: pure MFMA GEMM -> bf16 logits (+bias), written into the head
// bytes of each out row (row r: bytes r*4096 + qq*320 .. +319). Quarter-width
// blocks, dbuf issue-early, ONE barrier per k-tile, 16 tiles.
__global__ __launch_bounds__(256) void gemm_logits(
    const float* __restrict__ x,              // [M, K] fp32
    const unsigned short* __restrict__ Wt3,   // retiled bf16
    const float* __restrict__ bias,           // [GN]
    char* __restrict__ outb)                  // logits staging inside out rows
{
    __shared__ __align__(16) char Bs[2 * SLAB];   // 40 KB dbuf

    const int tid  = threadIdx.x;
    const int wid  = tid >> 6;       // 0..3: rows wid*16..+15
    const int lane = tid & 63;
    const int l15  = lane & 15;
    const int l4   = lane >> 4;

    // block decode: bid = xcd + 8*(qq + 4*rtl); quarters of a row panel share an XCD
    const int b    = blockIdx.x;
    const int xcd  = b & 7;
    const int l    = b >> 3;
    const int qq   = l & 3;
    const int rt   = xcd * 64 + (l >> 2);     // 0..511
    const int row0 = rt * BM;

    f32x4 acc[10];
#pragma unroll
    for (int nf = 0; nf < 10; ++nf) acc[nf] = (f32x4){0.f, 0.f, 0.f, 0.f};

    // A: lane owns row (row0 + wid*16 + l15), k-slices l4*8 in each 32-k half
    const float* aptr = x + (size_t)(row0 + wid * 16 + l15) * KDIM + l4 * 8;
    const char* bsrc0 = (const char*)Wt3 + (size_t)qq * SLAB + wid * 5120 + (size_t)lane * 16;

#define STAGE_B(T, BUF) do {                                            \
        const char* s_ = bsrc0 + (size_t)(T) * (4 * SLAB);              \
        char* d_ = Bs + (BUF) * SLAB + wid * 5120;                      \
        gll16(s_,        d_);                                           \
        gll16(s_ + 1024, d_ + 1024);                                    \
        gll16(s_ + 2048, d_ + 2048);                                    \
        gll16(s_ + 3072, d_ + 3072);                                    \
        gll16(s_ + 4096, d_ + 4096);                                    \
    } while (0)

#define LOAD_A(T, dst) do {                                             \
        const float* p_ = aptr + (size_t)(T) * BK;                      \
        dst[0] = *reinterpret_cast<const float4*>(p_);                  \
        dst[1] = *reinterpret_cast<const float4*>(p_ + 4);              \
        dst[2] = *reinterpret_cast<const float4*>(p_ + 32);             \
        dst[3] = *reinterpret_cast<const float4*>(p_ + 36);             \
    } while (0)

#define COMPUTE(BUF, AS) do {                                           \
        union { bf16x8 v; unsigned u[4]; } wA_;                         \
        const char* bb_ = Bs + (BUF) * SLAB;                            \
        _Pragma("unroll")                                               \
        for (int half = 0; half < 2; ++half) {                          \
            wA_.u[0] = pk2(AS[half*2].x, AS[half*2].y);                 \
            wA_.u[1] = pk2(AS[half*2].z, AS[half*2].w);                 \
            wA_.u[2] = pk2(AS[half*2+1].x, AS[half*2+1].y);             \
            wA_.u[3] = pk2(AS[half*2+1].z, AS[half*2+1].w);             \
            bf16x8 af_ = wA_.v;                                         \
            _Pragma("unroll")                                           \
            for (int nf = 0; nf < 10; ++nf) {                           \
                bf16x8 bfr = *reinterpret_cast<const bf16x8*>(          \
                    bb_ + nf * 2048 + half * 1024 + (size_t)lane * 16); \
                acc[nf] = __builtin_amdgcn_mfma_f32_16x16x32_bf16(      \
                    af_, bfr, acc[nf], 0, 0, 0);                        \
            }                                                           \
        }                                                               \
    } while (0)

    float4 a0[4], a1[4];
    STAGE_B(0, 0);
    LOAD_A(0, a0);
    __syncthreads();   // tile 0 resident

    for (int jj = 0; jj < NT; jj += 2) {
        LOAD_A(jj + 1, a1);                    // issue-early: fly under compute
        STAGE_B(jj + 1, 1);
        COMPUTE(0, a0);
        __syncthreads();                       // tile jj+1 resident
        if (jj + 2 < NT) {
            LOAD_A(jj + 2, a0);
            STAGE_B(jj + 2, 0);
        }
        COMPUTE(1, a1);
        __syncthreads();                       // tile jj+2 resident (or drain)
    }

    // ---- epilogue: +bias, bf16, repack via LDS, coalesced 320B-per-row write
    unsigned short* lds = (unsigned short*)Bs;   // 64 x 160 ushort = 20 KB
    float bv[10];
#pragma unroll
    for (int nf = 0; nf < 10; ++nf) bv[nf] = bias[qq * QBN + nf * 16 + l15];
#pragma unroll
    for (int nf = 0; nf < 10; ++nf)
#pragma unroll
        for (int j = 0; j < 4; ++j) {
            int lr = wid * 16 + l4 * 4 + j;    // C/D: row = l4*4 + reg
            lds[lr * QBN + nf * 16 + l15] = f2bf(acc[nf][j] + bv[nf]);
        }
    __syncthreads();
#pragma unroll
    for (int s = 0; s < 5; ++s) {
        int fi = tid + 256 * s;                // 0..1279 chunks of 16B
        int lr = fi / 20, ch = fi % 20;
        *reinterpret_cast<uint4*>(outb + (size_t)(row0 + lr) * 4096 + qq * 320 + ch * 16) =
            *reinterpret_cast<const uint4*>((const char*)lds + lr * 320 + ch * 16);
    }
#undef STAGE_B
#undef LOAD_A
#undef COMPUTE
}

// ---- pass B: streaming argmax + histogram + gather. Block = 4 rows.
// Reads each row's logits (head bytes) BEFORE overwriting the row with the gather.
__global__ __launch_bounds__(256) void argmax_gather(
    const float* __restrict__ gumbel,
    const float* __restrict__ codebook,
    int* __restrict__ counts,
    float* __restrict__ out)
{
    __shared__ int ns[4][2];
    const int tid = threadIdx.x;
    const int wid = tid >> 6;
    const int lane = tid & 63;
    const int rb = blockIdx.x * 4;
    const char* outb = (const char*)out;

    for (int p = wid; p < 8; p += 4) {         // wave handles 2 (row, group) pairs
        const int lr = p >> 1, g = p & 1;
        const size_t r = rb + lr;
        const unsigned short* lrow = (const unsigned short*)(outb + r * 4096 + g * 640);
        const float* grow = gumbel + r * GN + g * NCODES;
        float best = -INFINITY;
        int bn = 0;
#pragma unroll
        for (int i = 0; i < 5; ++i) {
            int n = lane + 64 * i;             // per-lane candidates ascending
            float v = bf2f(lrow[n]) + grow[n];
            if (v > best) { best = v; bn = n; }
        }
#pragma unroll
        for (int m = 1; m < 64; m <<= 1) {
            float ov = __shfl_xor(best, m, 64);
            int   on = __shfl_xor(bn, m, 64);
            if (ov > best || (ov == best && on < bn)) { best = ov; bn = on; }
        }
        if (lane == 0) {
            ns[lr][g] = bn;
            atomicAdd(&counts[g * NCODES + bn], 1);
        }
    }
    __syncthreads();

    // overwrite the 4 rows with gathered codebook rows (coalesced float4)
#pragma unroll
    for (int s = 0; s < 4; ++s) {
        int fi = tid + 256 * s;                // 0..1023 float4
        int lr = fi >> 8, q = fi & 255;
        int g = q >> 7, d4 = q & 127;
        int n = ns[lr][g];
        float4 cv = *reinterpret_cast<const float4*>(
            &codebook[((size_t)g * NCODES + n) * CD + d4 * 4]);
        *reinterpret_cast<float4*>(&out[(size_t)(rb + lr) * KDIM + q * 4]) = cv;
    }
}

__global__ void loss_kernel(const int* __restrict__ counts, float* __restrict__ out_loss) {
    __shared__ float red[256];
    float sum = 0.0f;
    for (int i = threadIdx.x; i < GN; i += 256) {
        float avg = (float)counts[i] * (1.0f / (float)M_ROWS);
        sum += avg * logf(avg + 1e-7f);
    }
    red[threadIdx.x] = sum;
    __syncthreads();
    for (int s = 128; s > 0; s >>= 1) {
        if (threadIdx.x < s) red[threadIdx.x] += red[threadIdx.x + s];
        __syncthreads();
    }
    if (threadIdx.x == 0) out_loss[0] = -red[0] * (1.0f / (float)NGRP);
}

extern "C" void kernel_launch(void* const* d_in, const int* in_sizes, int n_in,
                              void* d_out, int out_size, void* d_ws, size_t ws_size,
                              hipStream_t stream) {
    const float* x        = (const float*)d_in[0];
    const float* gumbel   = (const float*)d_in[1];
    const float* codebook = (const float*)d_in[2];
    const float* W        = (const float*)d_in[3];
    const float* bias     = (const float*)d_in[4];
    float* out = (float*)d_out;

    unsigned short* Wt3 = (unsigned short*)d_ws;              // 1.31 MB retiled
    int* counts = (int*)((char*)d_ws + 1310720 + 256);        // 2.5 KB

    prep_kernel<<<dim3(KDIM), dim3(256), 0, stream>>>(W, Wt3, counts);
    gemm_logits<<<dim3(2048), dim3(256), 0, stream>>>(
        x, Wt3, bias, (char*)out);
    argmax_gather<<<dim3(M_ROWS / 4), dim3(256), 0, stream>>>(
        gumbel, codebook, counts, out);
    loss_kernel<<<dim3(1), dim3(256), 0, stream>>>(
        counts, out + (size_t)M_ROWS * KDIM);
}